// Round 10
// baseline (25566.806 us; speedup 1.0000x reference)
//
#include <hip/hip_runtime.h>

using u16 = unsigned short;
typedef short bf16x8 __attribute__((ext_vector_type(8)));
typedef float f32x4 __attribute__((ext_vector_type(4)));

// ---------------- workspace layout (bytes) ----------------
static constexpr size_t OFF_BS  = 0;                               // 4*4096 f32 (bih+bhh)
static constexpr size_t OFF_XB  = 65536;                           // 256*64*512 bf16 time-major
static constexpr size_t OFF_H   = OFF_XB + (size_t)256*64*512*2;   // 4 cells * 2 bufs * 64*1024 bf16
static constexpr size_t OFF_C   = OFF_H  + (size_t)4*2*65536*2;    // 4 * 64*1024 f32
static constexpr size_t OFF_BAR = OFF_C  + (size_t)4*65536*4;      // barrier counters
static constexpr size_t WS_TOTAL= OFF_BAR + 4096;

__device__ __forceinline__ u16 f2b(float f) {               // f32 -> bf16 bits, RNE
  union { float f; unsigned u; } a; a.f = f;
  unsigned r = a.u + 0x7fffu + ((a.u >> 16) & 1u);
  return (u16)(r >> 16);
}

// ---------------- prep kernels ----------------
__global__ void k_bsum(const float* b1i, const float* b1h, const float* b2i, const float* b2h,
                       const float* b3i, const float* b3h, const float* b4i, const float* b4h,
                       float* __restrict__ bs)
{
  const int i = blockIdx.x * blockDim.x + threadIdx.x;   // 0..16383
  const int n = i >> 12, j = i & 4095;
  const float* bi = (n == 0) ? b1i : (n == 1) ? b2i : (n == 2) ? b3i : b4i;
  const float* bh = (n == 0) ? b1h : (n == 1) ? b2h : (n == 2) ? b3h : b4h;
  bs[i] = bi[j] + bh[j];
}

__global__ void k_xconv(const float* __restrict__ x, u16* __restrict__ xb)
{
  const int blk = blockIdx.x;            // t*64 + b
  const int t = blk >> 6, b = blk & 63;
  const int i = threadIdx.x * 4;         // 128 thr * 4 elems = 512
  const float4 v = *(const float4*)(x + ((size_t)b * 256 + t) * 512 + i);
  ushort4 s;
  s.x = f2b(v.x); s.y = f2b(v.y); s.z = f2b(v.z); s.w = f2b(v.w);
  *(ushort4*)(xb + (size_t)blk * 512 + i) = s;
}

__global__ void k_zero(uint4* __restrict__ p, int n16)
{
  const int i = blockIdx.x * blockDim.x + threadIdx.x;
  if (i < n16) { uint4 z; z.x = z.y = z.z = z.w = 0u; p[i] = z; }
}

// ---------------- grid barrier (2-level, agent scope; 256 WGs, 8 groups of 32) ----------------
__device__ __forceinline__ void grid_barrier(unsigned* bar, unsigned gen)
{
  __syncthreads();
  if (threadIdx.x == 0) {
    unsigned* gcnt = bar + ((blockIdx.x & 7) << 5);   // 8 counters, 128B apart
    unsigned* root = bar + 256;
    unsigned* rel  = bar + 288;
    const unsigned p = __hip_atomic_fetch_add(gcnt, 1u, __ATOMIC_ACQ_REL, __HIP_MEMORY_SCOPE_AGENT);
    if (p == gen * 32u + 31u) {                       // last of this group of 32
      const unsigned q = __hip_atomic_fetch_add(root, 1u, __ATOMIC_ACQ_REL, __HIP_MEMORY_SCOPE_AGENT);
      if (q == gen * 8u + 7u)
        __hip_atomic_store(rel, gen + 1u, __ATOMIC_RELEASE, __HIP_MEMORY_SCOPE_AGENT);
    }
    while (__hip_atomic_load(rel, __ATOMIC_ACQUIRE, __HIP_MEMORY_SCOPE_AGENT) < gen + 1u)
      __builtin_amdgcn_s_sleep(8);
  }
  __syncthreads();
}

// ---------------- one cell phase (weights already in registers) ----------------
// WG: 8 waves = (gate 0..3) x (k-half 0..1); covers all 64 batch rows x 16 cols x 4 gates.
// kh=0 waves own k in [0, S0*512) (the layer-input part), kh=1 waves own the state part.
// gl index: ((kh*4+g)*64 + row)*17 + col
#define GLI(kh, g, row, col) ((((kh) * 4 + (g)) * 64 + (row)) * 17 + (col))

template<int NSEC, int S0>
__device__ __forceinline__ void run_phase(
    char* __restrict__ A_lds, float* __restrict__ gl, const float* __restrict__ bias_lds,
    const u16* const (&src)[NSEC], const int (&sstr)[NSEC], const int (&soff)[NSEC],
    const uint4 (&w)[32],
    float* __restrict__ cst, u16* __restrict__ hnext, float* __restrict__ outp,
    const int cg, const int tid, const int g, const int kh,
    const int l15, const int l4, const int xr)
{
  f32x4 acc[4];
  #pragma unroll
  for (int mt = 0; mt < 4; ++mt) acc[mt] = f32x4{0.f, 0.f, 0.f, 0.f};

  #pragma unroll
  for (int s = 0; s < NSEC; ++s) {
    __syncthreads();
    {   // stage section s: 64 rows x 512 k bf16 -> LDS (swizzled); 512 thr x 8 chunks
      const u16* S = src[s];
      const int st = sstr[s];
      const int so = soff[s];
      #pragma unroll
      for (int i = 0; i < 8; ++i) {
        const int ch = tid + (i << 9);            // 0..4095 chunks of 16B
        const int lr = ch >> 6;                   // row 0..63
        const int kc = (ch & 63) << 3;            // k elem 0..504
        const uint4 v = *(const uint4*)(S + (size_t)lr * st + so + kc);
        *(uint4*)(A_lds + lr * 1024 + ((kc * 2) ^ ((lr & 7) << 4))) = v;
      }
    }
    __syncthreads();
    if (kh == 0) {
      if (s < S0) {
        #pragma unroll
        for (int k = 0; k < 16; ++k) {
          const int kb = (k << 6) + (l4 << 4);
          #pragma unroll
          for (int mt = 0; mt < 4; ++mt) {
            bf16x8 a = *(const bf16x8*)(A_lds + ((mt * 16 + l15) << 10) + (kb ^ xr));
            acc[mt] = __builtin_amdgcn_mfma_f32_16x16x32_bf16(
                a, __builtin_bit_cast(bf16x8, w[s * 16 + k]), acc[mt], 0, 0, 0);
          }
        }
      }
    } else {
      if (s >= S0) {
        #pragma unroll
        for (int k = 0; k < 16; ++k) {
          const int kb = (k << 6) + (l4 << 4);
          #pragma unroll
          for (int mt = 0; mt < 4; ++mt) {
            bf16x8 a = *(const bf16x8*)(A_lds + ((mt * 16 + l15) << 10) + (kb ^ xr));
            acc[mt] = __builtin_amdgcn_mfma_f32_16x16x32_bf16(
                a, __builtin_bit_cast(bf16x8, w[(s - S0) * 16 + k]), acc[mt], 0, 0, 0);
          }
        }
      }
    }
  }

  __syncthreads();
  // D layout (m89-verified): elem r -> (row = mt*16 + 4*(l>>4)+r, col = l&15)
  #pragma unroll
  for (int mt = 0; mt < 4; ++mt)
    #pragma unroll
    for (int r = 0; r < 4; ++r)
      gl[GLI(kh, g, mt * 16 + (l4 << 2) + r, l15)] = acc[mt][r];
  __syncthreads();

  #pragma unroll
  for (int ee = 0; ee < 2; ++ee) {
    const int e = tid + (ee << 9);        // 0..1023 = 64 rows x 16 cols
    const int row = e >> 4, lc = e & 15;
    const float gi = gl[GLI(0, 0, row, lc)] + gl[GLI(1, 0, row, lc)] + bias_lds[lc];
    const float gf = gl[GLI(0, 1, row, lc)] + gl[GLI(1, 1, row, lc)] + bias_lds[16 + lc];
    const float gg = gl[GLI(0, 2, row, lc)] + gl[GLI(1, 2, row, lc)] + bias_lds[32 + lc];
    const float go = gl[GLI(0, 3, row, lc)] + gl[GLI(1, 3, row, lc)] + bias_lds[48 + lc];
    const float ii = 1.f / (1.f + __expf(-gi));
    const float ff = 1.f / (1.f + __expf(-gf));
    const float gc = tanhf(gg);
    const float oo = 1.f / (1.f + __expf(-go));
    const int idx = (row << 10) + (cg << 4) + lc;
    const float cn = ff * cst[idx] + ii * gc;
    cst[idx] = cn;
    const float hn = oo * tanhf(cn);
    hnext[idx] = f2b(hn);
    if (outp) outp[idx] = hn;
  }
}

// ---------------- persistent MTRNN kernel ----------------
__global__ void __launch_bounds__(512, 2) k_mtrnn(
    char* __restrict__ ws, float* __restrict__ out,
    const float* __restrict__ w1i, const float* __restrict__ w1h,
    const float* __restrict__ w2i, const float* __restrict__ w2h,
    const float* __restrict__ w3i, const float* __restrict__ w3h,
    const float* __restrict__ w4i, const float* __restrict__ w4h)
{
  __shared__ alignas(16) char A_lds[65536];        // 64 rows x 512 k bf16 (swizzled)
  __shared__ float gl[2 * 4 * 64 * 17];            // k-half x gate x row x col(+pad)
  __shared__ float bias_lds[64];                   // 4 gates x 16 cols

  const int bid  = blockIdx.x;
  const int cell = bid >> 6;          // 0..3
  const int cg   = bid & 63;          // 16-col group
  const int tid  = threadIdx.x;
  const int lane = tid & 63;
  const int wv   = tid >> 6;          // 0..7
  const int g    = wv & 3;            // gate
  const int kh   = wv >> 2;           // k-half (0: layer-input part, 1: state part)
  const int l15  = lane & 15;
  const int l4   = lane >> 4;
  const int xr   = (l15 & 7) << 4;

  const float* bs = (const float*)(ws + OFF_BS);
  const u16* xb = (const u16*)(ws + OFF_XB);
  u16* hb       = (u16*)(ws + OFF_H);
  float* cs     = (float*)(ws + OFF_C);
  unsigned* bar = (unsigned*)(ws + OFF_BAR);

  // ---- load my weight slice into registers (once per call), f32 -> bf16 ----
  // wave (g, kh): W rows = gate g, cols [cg*16, +16); k-range = kh half.
  // B-frag lane l: col = l&15, k = ks*32 + (l>>4)*8 + j
  const float* wihp = (cell == 0) ? w1i : (cell == 1) ? w2i : (cell == 2) ? w3i : w4i;
  const float* whhp = (cell == 0) ? w1h : (cell == 1) ? w2h : (cell == 2) ? w3h : w4h;
  const int KIH = (cell == 0) ? 512 : 1024;
  const float* wsrc = kh ? whhp : wihp;
  const int Kw = kh ? 1024 : KIH;
  const int NK = Kw >> 5;                           // k-steps in my half (16 or 32)
  const size_t wrowoff = (size_t)((g << 10) + (cg << 4) + l15) * (size_t)Kw + (l4 << 3);

  uint4 w[32];
  #pragma unroll
  for (int ks = 0; ks < 32; ++ks) {
    if (ks < NK) {
      const float* p = wsrc + wrowoff + (ks << 5);
      const float4 f0 = *(const float4*)(p);
      const float4 f1 = *(const float4*)(p + 4);
      uint4 v;
      v.x = (unsigned)f2b(f0.x) | ((unsigned)f2b(f0.y) << 16);
      v.y = (unsigned)f2b(f0.z) | ((unsigned)f2b(f0.w) << 16);
      v.z = (unsigned)f2b(f1.x) | ((unsigned)f2b(f1.y) << 16);
      v.w = (unsigned)f2b(f1.z) | ((unsigned)f2b(f1.w) << 16);
      w[ks] = v;
    }
  }

  // ---- bias slice to LDS ----
  if (tid < 64) {
    const int bg = tid >> 4, bc = tid & 15;
    bias_lds[tid] = bs[(cell << 12) + (bg << 10) + (cg << 4) + bc];
  }

  float* cst = cs + (cell << 16);

  #define HBUF(n, p) (hb + (((n) * 2 + (p)) << 16))

  unsigned gen = 0;
  int c1 = 0, c2 = 0, c3 = 0, c4 = 0;

  #pragma unroll 1
  for (int t = 0; t < 256; ++t) {
    {   // cell1: A = [x_t (512) ; h1 (1024)], sections: x | h1 | h1
      if (cell == 0) {
        const u16* h1 = HBUF(0, c1);
        const u16* src[3] = { xb + (size_t)t * 32768, h1, h1 };
        const int sstr[3] = { 512, 1024, 1024 };
        const int soff[3] = { 0, 0, 512 };
        run_phase<3, 1>(A_lds, gl, bias_lds, src, sstr, soff, w, cst,
                        HBUF(0, c1 ^ 1), nullptr, cg, tid, g, kh, l15, l4, xr);
      }
      c1 ^= 1;
      grid_barrier(bar, gen); ++gen;
    }
    if ((t & 1) == 0) {   // cell2: A = [h1 ; h2]
      if (cell == 1) {
        const u16* hi = HBUF(0, c1);
        const u16* hs = HBUF(1, c2);
        const u16* src[4] = { hi, hi, hs, hs };
        const int sstr[4] = { 1024, 1024, 1024, 1024 };
        const int soff[4] = { 0, 512, 0, 512 };
        run_phase<4, 2>(A_lds, gl, bias_lds, src, sstr, soff, w, cst,
                        HBUF(1, c2 ^ 1), nullptr, cg, tid, g, kh, l15, l4, xr);
      }
      c2 ^= 1;
      grid_barrier(bar, gen); ++gen;
    }
    if ((t & 3) == 0) {   // cell3: A = [h2 ; h3]
      if (cell == 2) {
        const u16* hi = HBUF(1, c2);
        const u16* hs = HBUF(2, c3);
        const u16* src[4] = { hi, hi, hs, hs };
        const int sstr[4] = { 1024, 1024, 1024, 1024 };
        const int soff[4] = { 0, 512, 0, 512 };
        run_phase<4, 2>(A_lds, gl, bias_lds, src, sstr, soff, w, cst,
                        HBUF(2, c3 ^ 1), nullptr, cg, tid, g, kh, l15, l4, xr);
      }
      c3 ^= 1;
      grid_barrier(bar, gen); ++gen;
    }
    if ((t & 7) == 0) {   // cell4: A = [h3 ; h4]; also writes f32 output
      if (cell == 3) {
        const u16* hi = HBUF(2, c3);
        const u16* hs = HBUF(3, c4);
        const u16* src[4] = { hi, hi, hs, hs };
        const int sstr[4] = { 1024, 1024, 1024, 1024 };
        const int soff[4] = { 0, 512, 0, 512 };
        run_phase<4, 2>(A_lds, gl, bias_lds, src, sstr, soff, w, cst,
                        HBUF(3, c4 ^ 1), out, cg, tid, g, kh, l15, l4, xr);
      }
      c4 ^= 1;
      grid_barrier(bar, gen); ++gen;
    }
  }
  #undef HBUF
}

// ---------------- host ----------------
extern "C" void kernel_launch(void* const* d_in, const int* in_sizes, int n_in,
                              void* d_out, int out_size, void* d_ws, size_t ws_size,
                              hipStream_t stream)
{
  (void)in_sizes; (void)n_in; (void)out_size;
  if (ws_size < WS_TOTAL) return;

  const float* x = (const float*)d_in[0];
  const float* Wih[4] = { (const float*)d_in[1], (const float*)d_in[5],
                          (const float*)d_in[9], (const float*)d_in[13] };
  const float* Whh[4] = { (const float*)d_in[2], (const float*)d_in[6],
                          (const float*)d_in[10], (const float*)d_in[14] };
  const float* bih[4] = { (const float*)d_in[3], (const float*)d_in[7],
                          (const float*)d_in[11], (const float*)d_in[15] };
  const float* bhh[4] = { (const float*)d_in[4], (const float*)d_in[8],
                          (const float*)d_in[12], (const float*)d_in[16] };
  char* ws = (char*)d_ws;
  float* out = (float*)d_out;

  // bias sums
  k_bsum<<<64, 256, 0, stream>>>(bih[0], bhh[0], bih[1], bhh[1], bih[2], bhh[2], bih[3], bhh[3],
                                 (float*)(ws + OFF_BS));
  // x -> time-major bf16
  k_xconv<<<16384, 128, 0, stream>>>(x, (u16*)(ws + OFF_XB));
  // zero h (both buffers), c, barrier
  {
    const int n16 = (int)((WS_TOTAL - OFF_H) / 16);
    k_zero<<<(n16 + 255) / 256, 256, 0, stream>>>((uint4*)(ws + OFF_H), n16);
  }
  // persistent kernel: 256 WGs x 512 threads (1 WG/CU), weights in registers
  k_mtrnn<<<256, 512, 0, stream>>>(ws, out,
                                   Wih[0], Whh[0], Wih[1], Whh[1],
                                   Wih[2], Whh[2], Wih[3], Whh[3]);
}